// Round 5
// baseline (580.229 us; speedup 1.0000x reference)
//
#include <hip/hip_runtime.h>
#include <math.h>

// Problem constants
#define H 128
#define SW 113          // 128-16+1
#define CAND_CAP 128

typedef __attribute__((ext_vector_type(8))) short short8;  // 8 bf16 (4 VGPRs)
typedef __attribute__((ext_vector_type(4))) float f32x4;   // MFMA accumulator

// fp32 -> bf16, round-to-nearest-even (matches the error analysis)
static __device__ __forceinline__ uint32_t f2bf1(float v) {
    uint32_t u = __float_as_uint(v);
    return (u + 0x7fffu + ((u >> 16) & 1u)) >> 16;
}
static __device__ __forceinline__ uint32_t pack2(float a, float b) {
    return f2bf1(a) | (f2bf1(b) << 16);
}
static __device__ __forceinline__ float bf2f_lo(uint32_t d) {
    return __uint_as_float(d << 16);
}
static __device__ __forceinline__ float bf2f_hi(uint32_t d) {
    return __uint_as_float(d & 0xffff0000u);
}

// ---------------- prep: wn = w / sqrt(sum(w^2)/n), n = 16384 ----------------
__global__ __launch_bounds__(256) void prep_wn(const float* __restrict__ w,
                                               float* __restrict__ wn) {
    __shared__ float red[256];
    int t = threadIdx.x;
    float wv = w[t];
    red[t] = wv * wv;
    __syncthreads();
    for (int off = 128; off > 0; off >>= 1) {
        if (t < off) red[t] += red[t + off];
        __syncthreads();
    }
    float denom = sqrtf(red[0] / 16384.0f);
    wn[t] = wv / denom;
}

// ---------------- main ----------------
// One block (256 thr = 4 waves) per sample.
// LDS: input as bf16 only (32 KB): 128 rows x 16 chunks(16B), chunk-swizzled.
// Scores stay in REGISTERS (packed bf16, 32 dwords/thread); screening and
// candidate collection read registers, not LDS. Post-MFMA, the input region
// is aliased for the max-reduction / candidate scratch.
__global__ __launch_bounds__(256, 3) void gtpca_main(
    const float* __restrict__ in, const float* __restrict__ wn_g,
    float* __restrict__ out) {

    __shared__ __align__(16) uint32_t lds[8192];  // 32,768 B exactly
    float* red_a  = (float*)lds;                  // [256]  (alias, post-MFMA)
    int*   cand_n = (int*)(lds + 256);
    int*   cand_i = (int*)(lds + 260);            // [CAND_CAP]
    float* cand_v = (float*)(lds + 260 + CAND_CAP);

    const int tid  = threadIdx.x;
    const int lane = tid & 63;
    const int wid  = tid >> 6;
    const int b    = blockIdx.x;
    const float* ip  = in + (size_t)b * (H * H);
    const float4* in4 = (const float4*)ip;

    // ---- B fragments in registers: B_ki[k][n] = wn[ki][k-n], 0<=k-n<16 ----
    // mfma_f32_16x16x32_bf16 B layout: lane holds n = lane&15, k = (lane>>4)*8+e
    const int n15 = lane & 15;
    const int kg  = lane >> 4;                   // 0..3
    short8 Breg[16];
#pragma unroll
    for (int ki = 0; ki < 16; ++ki) {
        short8 f;
#pragma unroll
        for (int e = 0; e < 8; ++e) {
            int d = kg * 8 + e - n15;            // k - n
            float v = ((unsigned)d < 16u) ? wn_g[ki * 16 + d] : 0.0f;
            f[e] = (short)f2bf1(v);
        }
        Breg[ki] = f;
    }

    // ---- stage input as bf16 into LDS, chunk(16B) swizzle: phys = c ^ (r&7) ----
#pragma unroll
    for (int i = 0; i < 16; ++i) {
        int g = tid + 256 * i;                   // float4 id 0..4095
        float4 v = in4[g];
        int r = g >> 5, h = g & 31;              // row, half-chunk
        int phys = (h >> 1) ^ (r & 7);
        uint2 pk2 = make_uint2(pack2(v.x, v.y), pack2(v.z, v.w));
        *(uint2*)(lds + r * 64 + phys * 4 + (h & 1) * 2) = pk2;
    }
    __syncthreads();

    // ---- MFMA scores; screen + pack to registers in the epilogue ----
    const short8* ldsA = (const short8*)lds;     // index = r*16 + phys_chunk
    uint32_t pk[32];                             // packed bf16 scores (static idx)
    float best_a = -1.0f;
#pragma unroll
    for (int tyi = 0; tyi < 2; ++tyi) {
        int ty = 2 * wid + tyi;                  // 0..7
        int rbase = 16 * ty + n15;               // A row for this lane at ki=0
#pragma unroll
        for (int hf = 0; hf < 2; ++hf) {
            f32x4 C[4];
            f32x4 Cz = {0.0f, 0.0f, 0.0f, 0.0f};
#pragma unroll
            for (int j = 0; j < 4; ++j) C[j] = Cz;
#pragma unroll
            for (int ki = 0; ki < 16; ++ki) {
                int r = rbase + ki; if (r > 127) r = 127;   // only invalid rows clamp
                int rx = r << 4, rk = r & 7;
#pragma unroll
                for (int j = 0; j < 4; ++j) {
                    int cl = 2 * (4 * hf + j) + kg;          // logical chunk
                    if (cl > 15) cl = 15;                    // tx=7 tail: x>=113 discarded
                    short8 a = ldsA[rx | (cl ^ rk)];
                    C[j] = __builtin_amdgcn_mfma_f32_16x16x32_bf16(a, Breg[ki], C[j], 0, 0, 0);
                }
            }
            // epilogue: validity-masked best over fp32 C, pack C -> bf16 regs.
            // C layout: col n = lane&15 -> x; row = 4*(lane>>4)+reg -> y
            int ybase = 16 * ty + 4 * kg;
#pragma unroll
            for (int j = 0; j < 4; ++j) {
                int x = 16 * (4 * hf + j) + n15;
                if (x < SW) {
#pragma unroll
                    for (int ri = 0; ri < 4; ++ri) {
                        int y = ybase + ri;
                        if (y < SW) {
                            float a = fabsf(C[j][ri]);
                            if (a > best_a) best_a = a;
                        }
                    }
                }
                pk[((tyi * 2 + hf) * 4 + j) * 2 + 0] = pack2(C[j][0], C[j][1]);
                pk[((tyi * 2 + hf) * 4 + j) * 2 + 1] = pack2(C[j][2], C[j][3]);
            }
        }
    }
    __syncthreads();                             // all A-reads done; alias LDS

    // ---- block max-reduction -> tau ----
    red_a[tid] = best_a;
    if (tid == 0) *cand_n = 0;
    __syncthreads();
    for (int off = 128; off > 0; off >>= 1) {
        if (tid < off) red_a[tid] = fmaxf(red_a[tid], red_a[tid + off]);
        __syncthreads();
    }
    // screening margin: 2*eps_mfma + pack rounding (~46) < 48 -> complete set
    const float tau = red_a[0] - 48.0f;

    // ---- candidate collection from registers (complete by construction) ----
#pragma unroll
    for (int tyi = 0; tyi < 2; ++tyi) {
#pragma unroll
        for (int hf = 0; hf < 2; ++hf) {
#pragma unroll
            for (int j = 0; j < 4; ++j) {
                int x = 16 * (4 * hf + j) + n15;
                if (x < SW) {
                    int ybase = 16 * (2 * wid + tyi) + 4 * kg;
#pragma unroll
                    for (int p = 0; p < 2; ++p) {
                        uint32_t d = pk[((tyi * 2 + hf) * 4 + j) * 2 + p];
                        float v0 = bf2f_lo(d);          // C[2p]
                        float v1 = bf2f_hi(d);          // C[2p+1]
                        int y0 = ybase + 2 * p;
                        if (y0 < SW && fabsf(v0) >= tau) {
                            int pos = atomicAdd(cand_n, 1);
                            if (pos < CAND_CAP) cand_i[pos] = y0 * SW + x;
                        }
                        if (y0 + 1 < SW && fabsf(v1) >= tau) {
                            int pos = atomicAdd(cand_n, 1);
                            if (pos < CAND_CAP) cand_i[pos] = (y0 + 1) * SW + x;
                        }
                    }
                }
            }
        }
    }
    __syncthreads();
    int ncand = *cand_n; if (ncand > CAND_CAP) ncand = CAND_CAP;

    // ---- exact fp32 rescore (one wave per candidate, round-robin) ----
    for (int c = wid; c < ncand; c += 4) {
        int idx = cand_i[c];
        int yy = idx / SW, xx = idx - yy * SW;
        int kj = lane & 15, k0 = (lane >> 4) * 4;
        float s = 0.0f;
#pragma unroll
        for (int j2 = 0; j2 < 4; ++j2) {
            int ki = k0 + j2;
            s = __builtin_fmaf(ip[(yy + ki) * H + xx + kj], wn_g[ki * 16 + kj], s);
        }
#pragma unroll
        for (int mk = 32; mk > 0; mk >>= 1) s += __shfl_xor(s, mk, 64);
        if (lane == 0) cand_v[c] = s;
    }
    __syncthreads();

    // all threads redundantly pick best (max |v|, tie -> min idx = first occurrence)
    float bsa = -1.0f, bsv = 0.0f; int bsi = 0x7FFFFFFF;
    for (int c = 0; c < ncand; ++c) {
        float v = cand_v[c], a = fabsf(v);
        int idx = cand_i[c];
        if (a > bsa || (a == bsa && idx < bsi)) { bsa = a; bsi = idx; bsv = v; }
    }
    const int rr = bsi / SW;
    const int cc = bsi - rr * SW;
    const float sv = bsv * (1.0f / 16384.0f);    // exact: /2^14

    // ---- output: zeros + sv*wn block at (rr,cc) ----
    float4* out4 = (float4*)(out + (size_t)b * (H * H));
#pragma unroll
    for (int i = 0; i < 16; ++i) {
        int g = tid + i * 256;
        int orow = g >> 5;
        int ocol = (g & 31) << 2;
        float4 v = {0.0f, 0.0f, 0.0f, 0.0f};
        int dr = orow - rr;
        if ((unsigned)dr < 16u) {
            float* vp = (float*)&v;
#pragma unroll
            for (int k = 0; k < 4; ++k) {
                int dc = ocol + k - cc;
                if ((unsigned)dc < 16u) vp[k] = sv * wn_g[dr * 16 + dc];
            }
        }
        out4[g] = v;
    }
}

extern "C" void kernel_launch(void* const* d_in, const int* in_sizes, int n_in,
                              void* d_out, int out_size, void* d_ws, size_t ws_size,
                              hipStream_t stream) {
    const float* in = (const float*)d_in[0];   // (4096,128,128) fp32
    const float* w = (const float*)d_in[1];    // (16,16) fp32
    float* out = (float*)d_out;                // (4096,128,128) fp32
    float* wn = (float*)d_ws;                  // 256 floats scratch

    prep_wn<<<1, 256, 0, stream>>>(w, wn);
    gtpca_main<<<4096, 256, 0, stream>>>(in, wn, out);
}

// Round 6
// 500.766 us; speedup vs baseline: 1.1587x; 1.1587x over previous
//
#include <hip/hip_runtime.h>
#include <math.h>

// Problem constants
#define H 128
#define SW 113          // 128-16+1
#define CAND_CAP 128

typedef __attribute__((ext_vector_type(8))) short short8;  // 8 bf16 (4 VGPRs)
typedef __attribute__((ext_vector_type(4))) float f32x4;   // MFMA accumulator

// fp32 -> bf16, round-to-nearest-even (matches the error analysis)
static __device__ __forceinline__ uint32_t f2bf1(float v) {
    uint32_t u = __float_as_uint(v);
    return (u + 0x7fffu + ((u >> 16) & 1u)) >> 16;
}
static __device__ __forceinline__ uint32_t pack2(float a, float b) {
    return f2bf1(a) | (f2bf1(b) << 16);
}
static __device__ __forceinline__ float bf2f_lo(uint32_t d) {
    return __uint_as_float(d << 16);
}
static __device__ __forceinline__ float bf2f_hi(uint32_t d) {
    return __uint_as_float(d & 0xffff0000u);
}

// ---------------- prep: wn = w / sqrt(sum(w^2)/n), n = 16384 ----------------
__global__ __launch_bounds__(256) void prep_wn(const float* __restrict__ w,
                                               float* __restrict__ wn) {
    __shared__ float red[256];
    int t = threadIdx.x;
    float wv = w[t];
    red[t] = wv * wv;
    __syncthreads();
    for (int off = 128; off > 0; off >>= 1) {
        if (t < off) red[t] += red[t + off];
        __syncthreads();
    }
    float denom = sqrtf(red[0] / 16384.0f);
    wn[t] = wv / denom;
}

// ---------------- main ----------------
// One block (256 thr = 4 waves) per sample.
// LDS: input as bf16 only (32 KB): 128 rows x 16 chunks(16B).
// Chunk swizzle phys = c ^ (r & 15): a b128 quarter-wave (fixed kg) reads 16
// consecutive rows at 16 DISTINCT slots -> every bank hit exactly 2x = the
// b128 minimum -> conflict-free (r&7 gave only 8 slots -> 2-way conflict).
// Scores stay in REGISTERS (packed bf16, 32 dwords/thread, static indexing).
// Plain __launch_bounds__(256): the (256,3) min-waves hint made the backend
// target 6 waves/SIMD (84 VGPR) and spill pk[] to scratch (+131 MB HBM).
__global__ __launch_bounds__(256) void gtpca_main(
    const float* __restrict__ in, const float* __restrict__ wn_g,
    float* __restrict__ out) {

    __shared__ __align__(16) uint32_t lds[8192];  // 32,768 B exactly
    float* red_a  = (float*)lds;                  // [256]  (alias, post-MFMA)
    int*   cand_n = (int*)(lds + 256);
    int*   cand_i = (int*)(lds + 260);            // [CAND_CAP]
    float* cand_v = (float*)(lds + 260 + CAND_CAP);

    const int tid  = threadIdx.x;
    const int lane = tid & 63;
    const int wid  = tid >> 6;
    const int b    = blockIdx.x;
    const float* ip  = in + (size_t)b * (H * H);
    const float4* in4 = (const float4*)ip;

    const int n15 = lane & 15;
    const int kg  = lane >> 4;                   // 0..3

    // ---- stage input as bf16 into LDS, chunk(16B) swizzle: phys = c ^ (r&15) ----
#pragma unroll
    for (int i = 0; i < 16; ++i) {
        int g = tid + 256 * i;                   // float4 id 0..4095
        float4 v = in4[g];
        int r = g >> 5, h = g & 31;              // row, half-chunk
        int phys = (h >> 1) ^ (r & 15);
        uint2 pk2 = make_uint2(pack2(v.x, v.y), pack2(v.z, v.w));
        *(uint2*)(lds + r * 64 + phys * 4 + (h & 1) * 2) = pk2;
    }

    // ---- B fragments in registers (after staging: shorter liveness overlap) ----
    // B_ki[k][n] = wn[ki][k-n], 0<=k-n<16; lane holds n = lane&15, k = kg*8+e
    short8 Breg[16];
#pragma unroll
    for (int ki = 0; ki < 16; ++ki) {
        short8 f;
#pragma unroll
        for (int e = 0; e < 8; ++e) {
            int d = kg * 8 + e - n15;            // k - n
            float v = ((unsigned)d < 16u) ? wn_g[ki * 16 + d] : 0.0f;
            f[e] = (short)f2bf1(v);
        }
        Breg[ki] = f;
    }
    __syncthreads();

    // ---- MFMA scores; screen + pack to registers in the epilogue ----
    const short8* ldsA = (const short8*)lds;     // index = r*16 + phys_chunk
    uint32_t pk[32];                             // packed bf16 scores (static idx)
    float best_a = -1.0f;
#pragma unroll
    for (int tyi = 0; tyi < 2; ++tyi) {
        int ty = 2 * wid + tyi;                  // 0..7
        int rbase = 16 * ty + n15;               // A row for this lane at ki=0
#pragma unroll
        for (int hf = 0; hf < 2; ++hf) {
            f32x4 C[4];
            f32x4 Cz = {0.0f, 0.0f, 0.0f, 0.0f};
#pragma unroll
            for (int j = 0; j < 4; ++j) C[j] = Cz;
#pragma unroll
            for (int ki = 0; ki < 16; ++ki) {
                int r = rbase + ki; if (r > 127) r = 127;   // only invalid rows clamp
                int rx = r << 4, rk = r & 15;
#pragma unroll
                for (int j = 0; j < 4; ++j) {
                    int cl = 2 * (4 * hf + j) + kg;          // logical chunk
                    if (cl > 15) cl = 15;                    // tx=7 tail: x>=113 discarded
                    short8 a = ldsA[rx | (cl ^ rk)];
                    C[j] = __builtin_amdgcn_mfma_f32_16x16x32_bf16(a, Breg[ki], C[j], 0, 0, 0);
                }
            }
            // epilogue: validity-masked best over fp32 C, pack C -> bf16 regs.
            // C layout: col n = lane&15 -> x; row = 4*(lane>>4)+reg -> y
            int ybase = 16 * ty + 4 * kg;
#pragma unroll
            for (int j = 0; j < 4; ++j) {
                int x = 16 * (4 * hf + j) + n15;
                if (x < SW) {
#pragma unroll
                    for (int ri = 0; ri < 4; ++ri) {
                        int y = ybase + ri;
                        if (y < SW) {
                            float a = fabsf(C[j][ri]);
                            if (a > best_a) best_a = a;
                        }
                    }
                }
                pk[((tyi * 2 + hf) * 4 + j) * 2 + 0] = pack2(C[j][0], C[j][1]);
                pk[((tyi * 2 + hf) * 4 + j) * 2 + 1] = pack2(C[j][2], C[j][3]);
            }
        }
    }
    __syncthreads();                             // all A-reads done; alias LDS

    // ---- block max-reduction -> tau ----
    red_a[tid] = best_a;
    if (tid == 0) *cand_n = 0;
    __syncthreads();
    for (int off = 128; off > 0; off >>= 1) {
        if (tid < off) red_a[tid] = fmaxf(red_a[tid], red_a[tid + off]);
        __syncthreads();
    }
    // screening margin: 2*eps_mfma + pack rounding (~46) < 48 -> complete set
    const float tau = red_a[0] - 48.0f;

    // ---- candidate collection from registers (complete by construction) ----
#pragma unroll
    for (int tyi = 0; tyi < 2; ++tyi) {
#pragma unroll
        for (int hf = 0; hf < 2; ++hf) {
#pragma unroll
            for (int j = 0; j < 4; ++j) {
                int x = 16 * (4 * hf + j) + n15;
                if (x < SW) {
                    int ybase = 16 * (2 * wid + tyi) + 4 * kg;
#pragma unroll
                    for (int p = 0; p < 2; ++p) {
                        uint32_t d = pk[((tyi * 2 + hf) * 4 + j) * 2 + p];
                        float v0 = bf2f_lo(d);          // C[2p]
                        float v1 = bf2f_hi(d);          // C[2p+1]
                        int y0 = ybase + 2 * p;
                        if (y0 < SW && fabsf(v0) >= tau) {
                            int pos = atomicAdd(cand_n, 1);
                            if (pos < CAND_CAP) cand_i[pos] = y0 * SW + x;
                        }
                        if (y0 + 1 < SW && fabsf(v1) >= tau) {
                            int pos = atomicAdd(cand_n, 1);
                            if (pos < CAND_CAP) cand_i[pos] = (y0 + 1) * SW + x;
                        }
                    }
                }
            }
        }
    }
    __syncthreads();
    int ncand = *cand_n; if (ncand > CAND_CAP) ncand = CAND_CAP;

    // ---- exact fp32 rescore (one wave per candidate, round-robin) ----
    for (int c = wid; c < ncand; c += 4) {
        int idx = cand_i[c];
        int yy = idx / SW, xx = idx - yy * SW;
        int kj = lane & 15, k0 = (lane >> 4) * 4;
        float s = 0.0f;
#pragma unroll
        for (int j2 = 0; j2 < 4; ++j2) {
            int ki = k0 + j2;
            s = __builtin_fmaf(ip[(yy + ki) * H + xx + kj], wn_g[ki * 16 + kj], s);
        }
#pragma unroll
        for (int mk = 32; mk > 0; mk >>= 1) s += __shfl_xor(s, mk, 64);
        if (lane == 0) cand_v[c] = s;
    }
    __syncthreads();

    // all threads redundantly pick best (max |v|, tie -> min idx = first occurrence)
    float bsa = -1.0f, bsv = 0.0f; int bsi = 0x7FFFFFFF;
    for (int c = 0; c < ncand; ++c) {
        float v = cand_v[c], a = fabsf(v);
        int idx = cand_i[c];
        if (a > bsa || (a == bsa && idx < bsi)) { bsa = a; bsi = idx; bsv = v; }
    }
    const int rr = bsi / SW;
    const int cc = bsi - rr * SW;
    const float sv = bsv * (1.0f / 16384.0f);    // exact: /2^14

    // ---- output: zeros + sv*wn block at (rr,cc) ----
    float4* out4 = (float4*)(out + (size_t)b * (H * H));
#pragma unroll
    for (int i = 0; i < 16; ++i) {
        int g = tid + i * 256;
        int orow = g >> 5;
        int ocol = (g & 31) << 2;
        float4 v = {0.0f, 0.0f, 0.0f, 0.0f};
        int dr = orow - rr;
        if ((unsigned)dr < 16u) {
            float* vp = (float*)&v;
#pragma unroll
            for (int k = 0; k < 4; ++k) {
                int dc = ocol + k - cc;
                if ((unsigned)dc < 16u) vp[k] = sv * wn_g[dr * 16 + dc];
            }
        }
        out4[g] = v;
    }
}

extern "C" void kernel_launch(void* const* d_in, const int* in_sizes, int n_in,
                              void* d_out, int out_size, void* d_ws, size_t ws_size,
                              hipStream_t stream) {
    const float* in = (const float*)d_in[0];   // (4096,128,128) fp32
    const float* w = (const float*)d_in[1];    // (16,16) fp32
    float* out = (float*)d_out;                // (4096,128,128) fp32
    float* wn = (float*)d_ws;                  // 256 floats scratch

    prep_wn<<<1, 256, 0, stream>>>(w, wn);
    gtpca_main<<<4096, 256, 0, stream>>>(in, wn, out);
}

// Round 7
// 473.225 us; speedup vs baseline: 1.2261x; 1.0582x over previous
//
#include <hip/hip_runtime.h>
#include <math.h>

// Problem constants
#define H 128
#define SW 113          // 128-16+1
#define CAND_CAP 128

typedef __attribute__((ext_vector_type(8))) short short8;  // 8 bf16 (4 VGPRs)
typedef __attribute__((ext_vector_type(4))) float f32x4;   // MFMA accumulator

// Toeplitz B fragments, built once in prep_wn: Breg_g[ki][lane] is the
// mfma_f32_16x16x32_bf16 B-operand fragment (lane n=lane&15, k=(lane>>4)*8+e),
// B_ki[k][n] = wn[ki][k-n] for 0<=k-n<16 else 0. 16 KB, L2-hot.
__device__ short8 Breg_g[16][64];

// fp32 -> bf16 round-to-nearest-even (scalar, for prep)
static __device__ __forceinline__ uint32_t f2bf1(float v) {
    uint32_t u = __float_as_uint(v);
    return (u + 0x7fffu + ((u >> 16) & 1u)) >> 16;
}
// packed cvt: d.lo = bf16(lo), d.hi = bf16(hi) — 1 instr vs ~9-op manual RNE
static __device__ __forceinline__ uint32_t cvtpk(float lo, float hi) {
    uint32_t r;
    asm("v_cvt_pk_bf16_f32 %0, %1, %2" : "=v"(r) : "v"(lo), "v"(hi));
    return r;
}
static __device__ __forceinline__ float bf2f_lo(uint32_t d) {
    return __uint_as_float(d << 16);
}
static __device__ __forceinline__ float bf2f_hi(uint32_t d) {
    return __uint_as_float(d & 0xffff0000u);
}

// ---------------- prep: wn = w / sqrt(sum(w^2)/n); build Breg_g ----------------
__global__ __launch_bounds__(256) void prep_wn(const float* __restrict__ w,
                                               float* __restrict__ wn) {
    __shared__ float red[256];
    int t = threadIdx.x;
    float wv = w[t];
    red[t] = wv * wv;
    __syncthreads();
    for (int off = 128; off > 0; off >>= 1) {
        if (t < off) red[t] += red[t + off];
        __syncthreads();
    }
    float inv = 1.0f / sqrtf(red[0] / 16384.0f);
    wn[t] = wv * inv;
    // build Breg_g: 1024 (ki,lane) fragments, 4 per thread
    for (int q = 0; q < 4; ++q) {
        int pair = t * 4 + q;                 // 0..1023
        int ki = pair >> 6, ln = pair & 63;
        int nn = ln & 15, kgq = ln >> 4;
        short8 f;
#pragma unroll
        for (int e = 0; e < 8; ++e) {
            int d = kgq * 8 + e - nn;         // k - n
            float v = ((unsigned)d < 16u) ? w[ki * 16 + d] * inv : 0.0f;
            f[e] = (short)f2bf1(v);
        }
        Breg_g[ki][ln] = f;
    }
}

// ---------------- main ----------------
// One block (256 thr = 4 waves) per sample. LDS: input bf16 tile only (32 KB),
// 128 rows x 16 chunks(16B), chunk swizzle phys = c ^ (r&15) (conflict-minimal).
// Scores stay in registers (packed bf16, 32 dwords/thread, static indexing).
// Screening on packed |bf16| as u16 (monotone); boundary positions zero-masked.
__global__ __launch_bounds__(256) void gtpca_main(
    const float* __restrict__ in, const float* __restrict__ wn_g,
    float* __restrict__ out) {

    __shared__ __align__(16) uint32_t lds[8192];  // 32,768 B exactly
    uint32_t* redu  = lds;                        // [4]   (alias, post-MFMA)
    int*   cand_n = (int*)(lds + 8);
    int*   cand_i = (int*)(lds + 16);             // [CAND_CAP]
    float* cand_v = (float*)(lds + 16 + CAND_CAP);

    const int tid  = threadIdx.x;
    const int lane = tid & 63;
    const int wid  = tid >> 6;
    const int b    = blockIdx.x;
    const float* ip  = in + (size_t)b * (H * H);
    const float4* in4 = (const float4*)ip;

    const int n15 = lane & 15;
    const int kg  = lane >> 4;                   // 0..3

    // ---- stage input as bf16 into LDS ----
#pragma unroll
    for (int i = 0; i < 16; ++i) {
        int g = tid + 256 * i;                   // float4 id 0..4095
        float4 v = in4[g];
        int r = g >> 5, h = g & 31;              // row, half-chunk
        int phys = (h >> 1) ^ (r & 15);
        uint2 pk2 = make_uint2(cvtpk(v.x, v.y), cvtpk(v.z, v.w));
        *(uint2*)(lds + r * 64 + phys * 4 + (h & 1) * 2) = pk2;
    }

    // ---- B fragments: one coalesced b128 load per ki (L2-hot) ----
    short8 Breg[16];
#pragma unroll
    for (int ki = 0; ki < 16; ++ki) Breg[ki] = Breg_g[ki][lane];

    // per-lane chunk byte-offsets (xoff[T] = min(2T+kg,15)<<4), hoisted
    int xoff[8];
#pragma unroll
    for (int T = 0; T < 8; ++T) {
        int cl = 2 * T + kg; if (cl > 15) cl = 15;   // tx=7 tail: x>=113 masked
        xoff[T] = cl << 4;
    }
    __syncthreads();

    // ---- MFMA scores; pack to registers ----
    const char* ldsc = (const char*)lds;
    uint32_t pk[32];                             // packed bf16 scores (static idx)
#pragma unroll
    for (int tyi = 0; tyi < 2; ++tyi) {
        int ty = 2 * wid + tyi;                  // 0..7
        int rbase = 16 * ty + n15;               // A row for this lane at ki=0
#pragma unroll
        for (int hf = 0; hf < 2; ++hf) {
            f32x4 C[4];
            f32x4 Cz = {0.0f, 0.0f, 0.0f, 0.0f};
#pragma unroll
            for (int j = 0; j < 4; ++j) C[j] = Cz;
#pragma unroll
            for (int ki = 0; ki < 16; ++ki) {
                int r = rbase + ki; if (r > 127) r = 127;   // only invalid rows clamp
                int base = (r << 8) ^ ((r & 15) << 4);      // disjoint bit-fields
#pragma unroll
                for (int j = 0; j < 4; ++j) {
                    short8 a = *(const short8*)(ldsc + (base ^ xoff[4 * hf + j]));
                    C[j] = __builtin_amdgcn_mfma_f32_16x16x32_bf16(a, Breg[ki], C[j], 0, 0, 0);
                }
            }
            // C layout: col n = lane&15 -> x; row = 4*kg+reg -> y
#pragma unroll
            for (int j = 0; j < 4; ++j) {
                pk[((tyi * 2 + hf) * 4 + j) * 2 + 0] = cvtpk(C[j][0], C[j][1]);
                pk[((tyi * 2 + hf) * 4 + j) * 2 + 1] = cvtpk(C[j][2], C[j][3]);
            }
        }
    }

    // ---- zero-mask invalid positions (then no validity logic downstream) ----
    // x >= 113: only tile T=7 (hf=1,j=3) for lanes n15>=1
    if (n15 != 0) { pk[14] = 0; pk[15] = 0; pk[30] = 0; pk[31] = 0; }
    // y >= 113: only ty=7 (wid=3, tyi=1); ybase=112+4kg -> keep y=112 (kg0,p0,lo)
    if (wid == 3) {
        uint32_t keep = (kg == 0) ? 0x0000ffffu : 0u;
#pragma unroll
        for (int q = 16; q < 32; q += 2) { pk[q] &= keep; pk[q + 1] = 0; }
    }

    // ---- per-thread packed max: |bf16| as u16 compares monotonically ----
    uint32_t mself = 0;
#pragma unroll
    for (int q = 0; q < 32; ++q) {
        uint32_t a = pk[q] & 0x7fff7fffu;
        uint32_t h2 = a >> 16, l2 = a & 0xffffu;
        mself = mself > h2 ? mself : h2;
        mself = mself > l2 ? mself : l2;
    }
    uint32_t mw = mself;
#pragma unroll
    for (int mk = 32; mk; mk >>= 1) {
        uint32_t o = (uint32_t)__shfl_xor((int)mw, mk, 64);
        if (o > mw) mw = o;
    }

    __syncthreads();                             // all MFMA reads done; alias LDS
    if (lane == 0) redu[wid] = mw;
    if (tid == 0) *cand_n = 0;
    __syncthreads();
    uint32_t mall = redu[0];
    { uint32_t t1 = redu[1]; if (t1 > mall) mall = t1;
      t1 = redu[2]; if (t1 > mall) mall = t1;
      t1 = redu[3]; if (t1 > mall) mall = t1; }
    // screening margin: 2*(eps_mfma + pack rounding) (~46) < 48 -> complete set
    const float tau = __uint_as_float(mall << 16) - 48.0f;

    // ---- candidate collection (only threads whose own max can reach tau) ----
    if (__uint_as_float(mself << 16) >= tau) {
#pragma unroll
        for (int tyi = 0; tyi < 2; ++tyi) {
#pragma unroll
            for (int hf = 0; hf < 2; ++hf) {
#pragma unroll
                for (int j = 0; j < 4; ++j) {
                    int x = 16 * (4 * hf + j) + n15;
                    int ybase = 16 * (2 * wid + tyi) + 4 * kg;
#pragma unroll
                    for (int p = 0; p < 2; ++p) {
                        uint32_t d = pk[((tyi * 2 + hf) * 4 + j) * 2 + p];
                        float v0 = bf2f_lo(d);
                        float v1 = bf2f_hi(d);
                        int y0 = ybase + 2 * p;
                        if (fabsf(v0) >= tau) {
                            int pos = atomicAdd(cand_n, 1);
                            if (pos < CAND_CAP) cand_i[pos] = y0 * SW + x;
                        }
                        if (fabsf(v1) >= tau) {
                            int pos = atomicAdd(cand_n, 1);
                            if (pos < CAND_CAP) cand_i[pos] = (y0 + 1) * SW + x;
                        }
                    }
                }
            }
        }
    }
    __syncthreads();
    int ncand = *cand_n; if (ncand > CAND_CAP) ncand = CAND_CAP;

    // ---- exact fp32 rescore (one wave per candidate, round-robin) ----
    for (int c = wid; c < ncand; c += 4) {
        int idx = cand_i[c];
        int yy = idx / SW, xx = idx - yy * SW;
        int kj = lane & 15, k0 = (lane >> 4) * 4;
        float s = 0.0f;
#pragma unroll
        for (int j2 = 0; j2 < 4; ++j2) {
            int ki = k0 + j2;
            s = __builtin_fmaf(ip[(yy + ki) * H + xx + kj], wn_g[ki * 16 + kj], s);
        }
#pragma unroll
        for (int mk = 32; mk > 0; mk >>= 1) s += __shfl_xor(s, mk, 64);
        if (lane == 0) cand_v[c] = s;
    }
    __syncthreads();

    // all threads redundantly pick best (max |v|, tie -> min idx = first occurrence)
    float bsa = -1.0f, bsv = 0.0f; int bsi = 0x7FFFFFFF;
    for (int c = 0; c < ncand; ++c) {
        float v = cand_v[c], a = fabsf(v);
        int idx = cand_i[c];
        if (a > bsa || (a == bsa && idx < bsi)) { bsa = a; bsi = idx; bsv = v; }
    }
    const int rr = bsi / SW;
    const int cc = bsi - rr * SW;
    const float sv = bsv * (1.0f / 16384.0f);    // exact: /2^14

    // ---- output: zeros + sv*wn block at (rr,cc) ----
    float4* out4 = (float4*)(out + (size_t)b * (H * H));
#pragma unroll
    for (int i = 0; i < 16; ++i) {
        int g = tid + i * 256;
        int orow = g >> 5;
        int ocol = (g & 31) << 2;
        float4 v = {0.0f, 0.0f, 0.0f, 0.0f};
        int dr = orow - rr;
        if ((unsigned)dr < 16u) {
            float* vp = (float*)&v;
#pragma unroll
            for (int k = 0; k < 4; ++k) {
                int dc = ocol + k - cc;
                if ((unsigned)dc < 16u) vp[k] = sv * wn_g[dr * 16 + dc];
            }
        }
        out4[g] = v;
    }
}

extern "C" void kernel_launch(void* const* d_in, const int* in_sizes, int n_in,
                              void* d_out, int out_size, void* d_ws, size_t ws_size,
                              hipStream_t stream) {
    const float* in = (const float*)d_in[0];   // (4096,128,128) fp32
    const float* w = (const float*)d_in[1];    // (16,16) fp32
    float* out = (float*)d_out;                // (4096,128,128) fp32
    float* wn = (float*)d_ws;                  // 256 floats scratch

    prep_wn<<<1, 256, 0, stream>>>(w, wn);
    gtpca_main<<<4096, 256, 0, stream>>>(in, wn, out);
}

// Round 11
// 472.006 us; speedup vs baseline: 1.2293x; 1.0026x over previous
//
#include <hip/hip_runtime.h>
#include <math.h>

// Problem constants
#define H 128
#define SW 113          // 128-16+1
#define CAND_CAP 128

typedef __attribute__((ext_vector_type(8))) short short8;  // 8 bf16 (4 VGPRs)
typedef __attribute__((ext_vector_type(4))) float f32x4;   // MFMA accumulator

// Toeplitz B fragments, built once in prep_wn: Breg_g[ki][lane] is the
// mfma_f32_16x16x32_bf16 B-operand fragment (lane n=lane&15, k=(lane>>4)*8+e),
// B_ki[k][n] = wn[ki][k-n] for 0<=k-n<16 else 0. 16 KB, L2-hot.
__device__ short8 Breg_g[16][64];

// fp32 -> bf16 round-to-nearest-even (scalar, for prep)
static __device__ __forceinline__ uint32_t f2bf1(float v) {
    uint32_t u = __float_as_uint(v);
    return (u + 0x7fffu + ((u >> 16) & 1u)) >> 16;
}
// packed cvt: d.lo = bf16(lo), d.hi = bf16(hi) — 1 instr vs ~9-op manual RNE
static __device__ __forceinline__ uint32_t cvtpk(float lo, float hi) {
    uint32_t r;
    asm("v_cvt_pk_bf16_f32 %0, %1, %2" : "=v"(r) : "v"(lo), "v"(hi));
    return r;
}
static __device__ __forceinline__ float bf2f_lo(uint32_t d) {
    return __uint_as_float(d << 16);
}
static __device__ __forceinline__ float bf2f_hi(uint32_t d) {
    return __uint_as_float(d & 0xffff0000u);
}

// ---------------- prep: wn = w / sqrt(sum(w^2)/n); build Breg_g ----------------
__global__ __launch_bounds__(256) void prep_wn(const float* __restrict__ w,
                                               float* __restrict__ wn) {
    __shared__ float red[256];
    int t = threadIdx.x;
    float wv = w[t];
    red[t] = wv * wv;
    __syncthreads();
    for (int off = 128; off > 0; off >>= 1) {
        if (t < off) red[t] += red[t + off];
        __syncthreads();
    }
    float inv = 1.0f / sqrtf(red[0] / 16384.0f);
    wn[t] = wv * inv;
    // build Breg_g: 1024 (ki,lane) fragments, 4 per thread
    for (int q = 0; q < 4; ++q) {
        int pair = t * 4 + q;                 // 0..1023
        int ki = pair >> 6, ln = pair & 63;
        int nn = ln & 15, kgq = ln >> 4;
        short8 f;
#pragma unroll
        for (int e = 0; e < 8; ++e) {
            int d = kgq * 8 + e - nn;         // k - n
            float v = ((unsigned)d < 16u) ? w[ki * 16 + d] * inv : 0.0f;
            f[e] = (short)f2bf1(v);
        }
        Breg_g[ki][ln] = f;
    }
}

// ---------------- main ----------------
// One block (256 thr = 4 waves) per sample. LDS: input bf16 tile only (32 KB),
// 128 rows x 16 chunks(16B), chunk swizzle phys = c ^ (r&15) (conflict-minimal).
// Scores stay in registers (packed bf16, 32 dwords/thread, static indexing).
// Screening on packed |bf16| as u16 (monotone); boundary positions zero-masked.
// Rescore: one candidate per 8-lane group (32 candidates/round, was 4/round).
__global__ __launch_bounds__(256) void gtpca_main(
    const float* __restrict__ in, const float* __restrict__ wn_g,
    float* __restrict__ out) {

    __shared__ __align__(16) uint32_t lds[8192];  // 32,768 B exactly
    uint32_t* redu  = lds;                        // [4]   (alias, post-MFMA)
    int*   cand_n = (int*)(lds + 8);
    int*   cand_i = (int*)(lds + 16);             // [CAND_CAP]
    float* cand_v = (float*)(lds + 16 + CAND_CAP);

    const int tid  = threadIdx.x;
    const int lane = tid & 63;
    const int wid  = tid >> 6;
    const int b    = blockIdx.x;
    const float* ip  = in + (size_t)b * (H * H);
    const float4* in4 = (const float4*)ip;

    const int n15 = lane & 15;
    const int kg  = lane >> 4;                   // 0..3

    // ---- stage input as bf16 into LDS ----
#pragma unroll
    for (int i = 0; i < 16; ++i) {
        int g = tid + 256 * i;                   // float4 id 0..4095
        float4 v = in4[g];
        int r = g >> 5, h = g & 31;              // row, half-chunk
        int phys = (h >> 1) ^ (r & 15);
        uint2 pk2 = make_uint2(cvtpk(v.x, v.y), cvtpk(v.z, v.w));
        *(uint2*)(lds + r * 64 + phys * 4 + (h & 1) * 2) = pk2;
    }

    // ---- B fragments: one coalesced b128 load per ki (L2-hot) ----
    short8 Breg[16];
#pragma unroll
    for (int ki = 0; ki < 16; ++ki) Breg[ki] = Breg_g[ki][lane];

    // per-lane chunk byte-offsets (xoff[T] = min(2T+kg,15)<<4), hoisted
    int xoff[8];
#pragma unroll
    for (int T = 0; T < 8; ++T) {
        int cl = 2 * T + kg; if (cl > 15) cl = 15;   // tx=7 tail: x>=113 masked
        xoff[T] = cl << 4;
    }
    __syncthreads();

    // ---- MFMA scores; pack to registers ----
    const char* ldsc = (const char*)lds;
    uint32_t pk[32];                             // packed bf16 scores (static idx)
#pragma unroll
    for (int tyi = 0; tyi < 2; ++tyi) {
        int ty = 2 * wid + tyi;                  // 0..7
        int rbase = 16 * ty + n15;               // A row for this lane at ki=0
#pragma unroll
        for (int hf = 0; hf < 2; ++hf) {
            f32x4 C[4];
            f32x4 Cz = {0.0f, 0.0f, 0.0f, 0.0f};
#pragma unroll
            for (int j = 0; j < 4; ++j) C[j] = Cz;
#pragma unroll
            for (int ki = 0; ki < 16; ++ki) {
                int r = rbase + ki; if (r > 127) r = 127;   // only invalid rows clamp
                int base = (r << 8) ^ ((r & 15) << 4);      // disjoint bit-fields
#pragma unroll
                for (int j = 0; j < 4; ++j) {
                    short8 a = *(const short8*)(ldsc + (base ^ xoff[4 * hf + j]));
                    C[j] = __builtin_amdgcn_mfma_f32_16x16x32_bf16(a, Breg[ki], C[j], 0, 0, 0);
                }
            }
            // C layout: col n = lane&15 -> x; row = 4*kg+reg -> y
#pragma unroll
            for (int j = 0; j < 4; ++j) {
                pk[((tyi * 2 + hf) * 4 + j) * 2 + 0] = cvtpk(C[j][0], C[j][1]);
                pk[((tyi * 2 + hf) * 4 + j) * 2 + 1] = cvtpk(C[j][2], C[j][3]);
            }
        }
    }

    // ---- zero-mask invalid positions (then no validity logic downstream) ----
    // x >= 113: only tile T=7 (hf=1,j=3) for lanes n15>=1
    if (n15 != 0) { pk[14] = 0; pk[15] = 0; pk[30] = 0; pk[31] = 0; }
    // y >= 113: only ty=7 (wid=3, tyi=1); ybase=112+4kg -> keep y=112 (kg0,p0,lo)
    if (wid == 3) {
        uint32_t keep = (kg == 0) ? 0x0000ffffu : 0u;
#pragma unroll
        for (int q = 16; q < 32; q += 2) { pk[q] &= keep; pk[q + 1] = 0; }
    }

    // ---- per-thread packed max: |bf16| as u16 compares monotonically ----
    uint32_t mself = 0;
#pragma unroll
    for (int q = 0; q < 32; ++q) {
        uint32_t a = pk[q] & 0x7fff7fffu;
        uint32_t h2 = a >> 16, l2 = a & 0xffffu;
        mself = mself > h2 ? mself : h2;
        mself = mself > l2 ? mself : l2;
    }
    uint32_t mw = mself;
#pragma unroll
    for (int mk = 32; mk; mk >>= 1) {
        uint32_t o = (uint32_t)__shfl_xor((int)mw, mk, 64);
        if (o > mw) mw = o;
    }

    __syncthreads();                             // all MFMA reads done; alias LDS
    if (lane == 0) redu[wid] = mw;
    if (tid == 0) *cand_n = 0;
    __syncthreads();
    uint32_t mall = redu[0];
    { uint32_t t1 = redu[1]; if (t1 > mall) mall = t1;
      t1 = redu[2]; if (t1 > mall) mall = t1;
      t1 = redu[3]; if (t1 > mall) mall = t1; }
    // screening margin: 2*(eps_mfma + pack rounding) (~46) < 48 -> complete set
    const float tau = __uint_as_float(mall << 16) - 48.0f;

    // ---- candidate collection (only threads whose own max can reach tau) ----
    if (__uint_as_float(mself << 16) >= tau) {
#pragma unroll
        for (int tyi = 0; tyi < 2; ++tyi) {
#pragma unroll
            for (int hf = 0; hf < 2; ++hf) {
#pragma unroll
                for (int j = 0; j < 4; ++j) {
                    int x = 16 * (4 * hf + j) + n15;
                    int ybase = 16 * (2 * wid + tyi) + 4 * kg;
#pragma unroll
                    for (int p = 0; p < 2; ++p) {
                        uint32_t d = pk[((tyi * 2 + hf) * 4 + j) * 2 + p];
                        float v0 = bf2f_lo(d);
                        float v1 = bf2f_hi(d);
                        int y0 = ybase + 2 * p;
                        if (fabsf(v0) >= tau) {
                            int pos = atomicAdd(cand_n, 1);
                            if (pos < CAND_CAP) cand_i[pos] = y0 * SW + x;
                        }
                        if (fabsf(v1) >= tau) {
                            int pos = atomicAdd(cand_n, 1);
                            if (pos < CAND_CAP) cand_i[pos] = (y0 + 1) * SW + x;
                        }
                    }
                }
            }
        }
    }
    __syncthreads();
    int ncand = *cand_n; if (ncand > CAND_CAP) ncand = CAND_CAP;

    // ---- exact fp32 rescore: one candidate per 8-lane group (32/round) ----
    // lane-in-group l8 covers kj = l8 and l8+8; e>>1 = ki. Exact 16x16 coverage.
    const int l8 = tid & 7;
    for (int base2 = 0; base2 < ncand; base2 += 32) {
        int c = base2 + (tid >> 3);              // group id 0..31
        float sacc = 0.0f;
        if (c < ncand) {
            int idx = cand_i[c];
            int yy = idx / SW, xx = idx - yy * SW;
            const float* wp = ip + yy * H + xx;
#pragma unroll
            for (int e = 0; e < 32; ++e) {
                int ki = e >> 1;
                int kj = l8 + ((e & 1) << 3);
                sacc = __builtin_fmaf(wp[ki * H + kj], wn_g[ki * 16 + kj], sacc);
            }
        }
        // reduce within 8-lane group (all lanes participate in shuffles)
        sacc += __shfl_xor(sacc, 1, 64);
        sacc += __shfl_xor(sacc, 2, 64);
        sacc += __shfl_xor(sacc, 4, 64);
        if (c < ncand && l8 == 0) cand_v[c] = sacc;
    }
    __syncthreads();

    // all threads redundantly pick best (max |v|, tie -> min idx = first occurrence)
    float bsa = -1.0f, bsv = 0.0f; int bsi = 0x7FFFFFFF;
    for (int c = 0; c < ncand; ++c) {
        float v = cand_v[c], a = fabsf(v);
        int idx = cand_i[c];
        if (a > bsa || (a == bsa && idx < bsi)) { bsa = a; bsi = idx; bsv = v; }
    }
    const int rr = bsi / SW;
    const int cc = bsi - rr * SW;
    const float sv = bsv * (1.0f / 16384.0f);    // exact: /2^14

    // ---- output: zeros + sv*wn block at (rr,cc) ----
    float4* out4 = (float4*)(out + (size_t)b * (H * H));
#pragma unroll
    for (int i = 0; i < 16; ++i) {
        int g = tid + i * 256;
        int orow = g >> 5;
        int ocol = (g & 31) << 2;
        float4 v = {0.0f, 0.0f, 0.0f, 0.0f};
        int dr = orow - rr;
        if ((unsigned)dr < 16u) {
            float* vp = (float*)&v;
#pragma unroll
            for (int k = 0; k < 4; ++k) {
                int dc = ocol + k - cc;
                if ((unsigned)dc < 16u) vp[k] = sv * wn_g[dr * 16 + dc];
            }
        }
        out4[g] = v;
    }
}

extern "C" void kernel_launch(void* const* d_in, const int* in_sizes, int n_in,
                              void* d_out, int out_size, void* d_ws, size_t ws_size,
                              hipStream_t stream) {
    const float* in = (const float*)d_in[0];   // (4096,128,128) fp32
    const float* w = (const float*)d_in[1];    // (16,16) fp32
    float* out = (float*)d_out;                // (4096,128,128) fp32
    float* wn = (float*)d_ws;                  // 256 floats scratch

    prep_wn<<<1, 256, 0, stream>>>(w, wn);
    gtpca_main<<<4096, 256, 0, stream>>>(in, wn, out);
}